// Round 8
// baseline (247.925 us; speedup 1.0000x reference)
//
#include <hip/hip_runtime.h>
#include <stdint.h>

// Dtype model: inputs fp32, output fp32, internals bf16 MFMA.
// gamma == 0 in this instance => out = h1 + h2 = x1@Wp1 + x2@Wp2 + b1 + b2.
// R13: R12's fused GEMM was VALU-bound (VALUBusy==Occupancy==38%) on inline
// fp32->bf16 conversion (16 f2bf + 4 ds_write per thread-iter). Hoist the
// conversion into the streaming transpose kernel (x1/x2 -> bf16 once,
// gamma==0-gated, overlaid on unused h1b/h2b space); the fused GEMM now
// stages BOTH operands via global_load_lds (no VALU convert, no ds_write).
// Grid remap by=f>>3 so a panel's 8 col-sharers are temporally adjacent
// (A working set ~37MB -> L3-resident). gamma!=0 path unchanged.

// ---------- types ----------
typedef __bf16 bf16x8 __attribute__((ext_vector_type(8)));
typedef float f32x4 __attribute__((ext_vector_type(4)));
typedef unsigned short u16x8 __attribute__((ext_vector_type(8)));
typedef unsigned short u16x4 __attribute__((ext_vector_type(4)));
typedef unsigned short u16x2 __attribute__((ext_vector_type(2)));

typedef __attribute__((address_space(3))) unsigned int as3_u32;
typedef const __attribute__((address_space(1))) unsigned int as1_u32;

__device__ __forceinline__ float bf2f(unsigned short h) {
  union { unsigned int u; float f; } v; v.u = ((unsigned int)h) << 16; return v.f;
}
__device__ __forceinline__ unsigned short f2bf(float f) {
  union { float f; unsigned int u; } v; v.f = f;
  unsigned int u = v.u;
  return (unsigned short)((u + 0x7fffu + ((u >> 16) & 1u)) >> 16);
}
__device__ __forceinline__ bf16x8 as_bf16x8(u16x8 x) {
  union { u16x8 u; bf16x8 b; } c; c.u = x; return c.b;
}
// async global->LDS, 16B per lane; lds base must be wave-uniform
__device__ __forceinline__ void async_load16(unsigned short* lds, const unsigned short* g) {
  __builtin_amdgcn_global_load_lds((as1_u32*)g, (as3_u32*)lds, 16, 0, 0);
}

// ---------- transpose + x-convert megakernel ----------
// bids 0..415: dst_bf16[512][K] = W[K][512]^T (LDS-tiled, coalesced both ways);
//   QKV segments (bid>=224) gamma!=0-only.
// bids 416..6559: xbf1 = bf16(x1), 2048 f32/block. gamma==0-only.
// bids 6560..14751: xbf2 = bf16(x2).                gamma==0-only.
__global__ __launch_bounds__(256) void transpose_all_lds(
    const float* __restrict__ Wp1, const float* __restrict__ Wp2,
    const float* __restrict__ Wq, const float* __restrict__ Wk,
    const float* __restrict__ Wv,
    const float* __restrict__ x1, const float* __restrict__ x2,
    unsigned short* __restrict__ o1, unsigned short* __restrict__ o2,
    unsigned short* __restrict__ oq, unsigned short* __restrict__ ok,
    unsigned short* __restrict__ ov,
    unsigned short* __restrict__ xbf1, unsigned short* __restrict__ xbf2,
    const float* __restrict__ gamma)
{
  const int bid = blockIdx.x;
  const int tid = threadIdx.x;

  if (bid >= 416) {
    // streaming fp32 -> bf16 copy of x1/x2 (only the gamma==0 fused path
    // consumes these; buffers overlay h1b/h2b which gamma==0 never uses)
    if (gamma[0] != 0.0f) return;
    const float* src; unsigned short* dst; int local;
    if (bid < 6560) { src = x1; dst = xbf1; local = bid - 416; }
    else            { src = x2; dst = xbf2; local = bid - 6560; }
    size_t base = (size_t)local * 2048 + (size_t)tid * 8;
    f32x4 a = *(const f32x4*)(src + base);
    f32x4 b = *(const f32x4*)(src + base + 4);
    u16x8 o;
#pragma unroll
    for (int j = 0; j < 4; ++j) { o[j] = f2bf(a[j]); o[4 + j] = f2bf(b[j]); }
    *(u16x8*)(dst + base) = o;
    return;
  }

  __shared__ unsigned short sT[64][72];  // [n][k], stride 144B (16B-aligned)
  const float* src; unsigned short* dst; int K, ktiles, base;
  if (bid < 96)       { src = Wp1; dst = o1; K = 768;  ktiles = 12; base = 0; }
  else if (bid < 224) { src = Wp2; dst = o2; K = 1024; ktiles = 16; base = 96; }
  else {
    if (gamma[0] == 0.0f) return;  // QKV weights only feed attention
    K = 512; ktiles = 8;
    if (bid < 288)      { src = Wq; dst = oq; base = 224; }
    else if (bid < 352) { src = Wk; dst = ok; base = 288; }
    else                { src = Wv; dst = ov; base = 352; }
  }
  const int local = bid - base;
  const int k0 = (local % ktiles) * 64;
  const int n0 = (local / ktiles) * 64;

  const int rr = tid >> 4, c4 = tid & 15;
#pragma unroll
  for (int i = 0; i < 4; ++i) {
    int row = i * 16 + rr;
    f32x4 v = *(const f32x4*)(src + (size_t)(k0 + row) * 512 + n0 + c4 * 4);
#pragma unroll
    for (int j = 0; j < 4; ++j)
      sT[c4 * 4 + j][row] = f2bf(v[j]);
  }
  __syncthreads();

  const int nr = tid >> 3, kq = tid & 7;
#pragma unroll
  for (int i = 0; i < 2; ++i) {
    int n = i * 32 + nr;
    *(u16x8*)(dst + (size_t)(n0 + n) * K + k0 + kq * 8) = *(const u16x8*)&sT[n][kq * 8];
  }
}

// ---------- fused gamma==0 output GEMM ----------
// out_f32[16384,512] = xbf1@Wp1 + xbf2@Wp2 + b1 + b2, K = 768+1024 = 1792.
// 64x64 tile, BK=64, dbuf LDS (32 KiB -> 5 blocks/CU). BOTH operands staged
// via global_load_lds with pre-swizzled global source (linear LDS dest,
// XOR swizzle cs = c ^ (r&7) matched on the read side). Grid 2048:
// by=f>>3, bx=f&7 -> a panel's 8 col-sharers are temporally adjacent.
__global__ __launch_bounds__(256, 5) void fused_h12_out(
    const unsigned short* __restrict__ xbf1, const unsigned short* __restrict__ xbf2,
    const unsigned short* __restrict__ WT1, const unsigned short* __restrict__ WT2,
    const float* __restrict__ b1, const float* __restrict__ b2,
    float* __restrict__ out, const float* __restrict__ gamma)
{
  if (gamma[0] != 0.0f) return;  // gamma!=0 handled by the full path
  __shared__ __align__(16) unsigned short sA[2][64 * 64];
  __shared__ __align__(16) unsigned short sB[2][64 * 64];
  const int tid = threadIdx.x;
  const int lane = tid & 63;
  const int w = tid >> 6;
  const int wm = w & 1, wn = w >> 1;
  const int l15 = lane & 15, lg = lane >> 4;

  const int f = blockIdx.x;                 // 0..2047
  const int bx = f & 7;                     // col tile 0..7
  const int by = f >> 3;                    // row panel 0..255
  const size_t row0A = (size_t)by * 64;
  const int row0B = bx * 64;

  f32x4 acc[2][2] = {};

  // tile = 64 rows x 64 bf16 = 512 16B chunks -> 2 gload_lds/thread.
  auto stageA = [&](int kk, int buf) {
#pragma unroll
    for (int j = 0; j < 2; ++j) {
      int cc = (w * 2 + j) * 64 + lane;      // 16B chunk id 0..511
      int r = cc >> 3, c = cc & 7;
      int cs = c ^ (r & 7);                  // pre-swizzled global source
      const unsigned short* ap = (kk < 768)
          ? (xbf1 + (size_t)(row0A + r) * 768 + kk + cs * 8)
          : (xbf2 + (size_t)(row0A + r) * 1024 + (kk - 768) + cs * 8);
      async_load16(&sA[buf][(size_t)(w * 2 + j) * 512], ap);
    }
  };
  auto stageB = [&](int kk, int buf) {
#pragma unroll
    for (int j = 0; j < 2; ++j) {
      int cc = (w * 2 + j) * 64 + lane;
      int r = cc >> 3, c = cc & 7;
      int cs = c ^ (r & 7);
      const unsigned short* bp = (kk < 768)
          ? (WT1 + (size_t)(row0B + r) * 768 + kk + cs * 8)
          : (WT2 + (size_t)(row0B + r) * 1024 + (kk - 768) + cs * 8);
      async_load16(&sB[buf][(size_t)(w * 2 + j) * 512], bp);
    }
  };
  auto compute = [&](int buf) {
#pragma unroll
    for (int ks = 0; ks < 2; ++ks) {
      bf16x8 af[2], bfr[2];
#pragma unroll
      for (int mb = 0; mb < 2; ++mb) {
        int row = wm * 32 + mb * 16 + l15;
        int cs = (ks * 4 + lg) ^ (row & 7);
        af[mb] = *(const bf16x8*)&sA[buf][row * 64 + cs * 8];
      }
#pragma unroll
      for (int nb = 0; nb < 2; ++nb) {
        int row = wn * 32 + nb * 16 + l15;
        int cs = (ks * 4 + lg) ^ (row & 7);
        bfr[nb] = *(const bf16x8*)&sB[buf][row * 64 + cs * 8];
      }
#pragma unroll
      for (int mb = 0; mb < 2; ++mb)
#pragma unroll
        for (int nb = 0; nb < 2; ++nb)
          acc[mb][nb] = __builtin_amdgcn_mfma_f32_16x16x32_bf16(af[mb], bfr[nb], acc[mb][nb], 0, 0, 0);
    }
  };

  // prologue: stage tile 0
  stageA(0, 0);
  stageB(0, 0);
  __syncthreads();

  const int NT = 28;  // 1792 / 64
  int cur = 0;
  for (int t = 0; t < NT; ++t) {
    if (t + 1 < NT) {            // issue next tile's loads BEFORE compute
      stageA((t + 1) * 64, cur ^ 1);
      stageB((t + 1) * 64, cur ^ 1);
    }
    compute(cur);
    __syncthreads();             // drains next-tile gload_lds
    cur ^= 1;
  }

  // epilogue: fp32 direct store, bias = b1 + b2
  const int colb = row0B + wn * 32;
#pragma unroll
  for (int nb = 0; nb < 2; ++nb) {
    int col = colb + nb * 16 + l15;
    float bv = b1[col] + b2[col];
#pragma unroll
    for (int mb = 0; mb < 2; ++mb) {
      size_t rowb = row0A + wm * 32 + mb * 16 + lg * 4;
#pragma unroll
      for (int r = 0; r < 4; ++r)
        out[(rowb + r) * 512 + col] = acc[mb][nb][r] + bv;
    }
  }
}

// ---------- gated h-GEMMs (gamma!=0 path): z=0 -> h1, z=1 -> h2 ----------
__global__ __launch_bounds__(256) void gemm_h12(
    const float* __restrict__ x1, const float* __restrict__ x2,
    const unsigned short* __restrict__ WT1, const unsigned short* __restrict__ WT2,
    const float* __restrict__ b1, const float* __restrict__ b2,
    unsigned short* __restrict__ h1b, unsigned short* __restrict__ h2b,
    const float* __restrict__ gate)
{
  if (gate[0] == 0.0f) return;
  const int z = blockIdx.z;
  const float* A = z ? x2 : x1;
  const unsigned short* Bt = z ? WT2 : WT1;
  const float* bias = z ? b2 : b1;
  unsigned short* C = z ? h2b : h1b;
  const int K = z ? 1024 : 768;
  const int ldc = 512;

  __shared__ __align__(16) unsigned short sA[128 * 32];
  __shared__ __align__(16) unsigned short sB[128 * 32];
  const int tid = threadIdx.x;
  const int lane = tid & 63;
  const int w = tid >> 6;
  const int wm = w & 1, wn = w >> 1;
  const int l15 = lane & 15, lg = lane >> 4;
  const size_t row0A = (size_t)blockIdx.x * 128;
  const size_t row0B = (size_t)blockIdx.y * 128;
  f32x4 acc[4][4] = {};

  for (int kb = 0; kb < K; kb += 32) {
#pragma unroll
    for (int j = 0; j < 2; ++j) {
      int cc = (w * 2 + j) * 64 + lane;
      int r = cc >> 2, k8 = cc & 3;
      async_load16(&sB[(size_t)((w * 2 + j) * 64) * 8], Bt + (row0B + r) * K + kb + k8 * 8);
    }
    {
      // coalesced A staging: 128x32 f32 tile = 1024 f32x4 chunks, 4/thread
#pragma unroll
      for (int i = 0; i < 4; ++i) {
        int cc = i * 256 + tid;
        int row = cc >> 3, c4 = cc & 7;     // 8 chunks per 32-float row
        f32x4 v = *(const f32x4*)(A + (row0A + row) * K + kb + c4 * 4);
        u16x4 hv;
#pragma unroll
        for (int j = 0; j < 4; ++j) hv[j] = f2bf(v[j]);
        *(u16x4*)&sA[row * 32 + c4 * 4] = hv;
      }
    }
    __syncthreads();
    bf16x8 af[4], bfr[4];
#pragma unroll
    for (int mb = 0; mb < 4; ++mb)
      af[mb] = *(const bf16x8*)&sA[(wm * 64 + mb * 16 + l15) * 32 + lg * 8];
#pragma unroll
    for (int nb = 0; nb < 4; ++nb)
      bfr[nb] = *(const bf16x8*)&sB[(wn * 64 + nb * 16 + l15) * 32 + lg * 8];
#pragma unroll
    for (int mb = 0; mb < 4; ++mb)
#pragma unroll
      for (int nb = 0; nb < 4; ++nb)
        acc[mb][nb] = __builtin_amdgcn_mfma_f32_16x16x32_bf16(af[mb], bfr[nb], acc[mb][nb], 0, 0, 0);
    __syncthreads();
  }

  const int colb = (int)row0B + wn * 64;
#pragma unroll
  for (int nb = 0; nb < 4; ++nb) {
    int col = colb + nb * 16 + l15;
    float bv = bias[col];
#pragma unroll
    for (int mb = 0; mb < 4; ++mb) {
      size_t rowb = row0A + wm * 64 + mb * 16 + lg * 4;
#pragma unroll
      for (int r = 0; r < 4; ++r)
        C[(rowb + r) * ldc + col] = f2bf(acc[mb][nb][r] + bv);
    }
  }
}

// ---------- QKV projections: 3 GEMMs in one launch via blockIdx.z ----------
__global__ __launch_bounds__(256) void gemm_qkv(
    const unsigned short* __restrict__ Aq,
    const unsigned short* __restrict__ Akv,
    const unsigned short* __restrict__ Wq_, const unsigned short* __restrict__ Wk_,
    const unsigned short* __restrict__ Wv_,
    const float* __restrict__ bq_, const float* __restrict__ bk_,
    const float* __restrict__ bv_,
    unsigned short* __restrict__ P,
    const float* __restrict__ gate)
{
  if (gate[0] == 0.0f) return;
  const int z = blockIdx.z;
  const unsigned short* A  = (z == 0) ? Aq : Akv;
  const unsigned short* Bt = (z == 0) ? Wq_ : (z == 1 ? Wk_ : Wv_);
  const float* bias        = (z == 0) ? bq_ : (z == 1 ? bk_ : bv_);
  unsigned short* C = P + z * 512;
  const int K = 512, ldc = 1536;

  __shared__ __align__(16) unsigned short sA[128 * 32];
  __shared__ __align__(16) unsigned short sB[128 * 32];
  const int tid = threadIdx.x;
  const int lane = tid & 63;
  const int w = tid >> 6;
  const int wm = w & 1, wn = w >> 1;
  const int l15 = lane & 15, lg = lane >> 4;
  const size_t row0A = (size_t)blockIdx.x * 128;
  const size_t row0B = (size_t)blockIdx.y * 128;
  f32x4 acc[4][4] = {};

  for (int kb = 0; kb < K; kb += 32) {
#pragma unroll
    for (int j = 0; j < 2; ++j) {
      int cc = (w * 2 + j) * 64 + lane;
      int r = cc >> 2, k8 = cc & 3;
      async_load16(&sA[(size_t)((w * 2 + j) * 64) * 8], A + (row0A + r) * K + kb + k8 * 8);
      async_load16(&sB[(size_t)((w * 2 + j) * 64) * 8], Bt + (row0B + r) * K + kb + k8 * 8);
    }
    __syncthreads();
    bf16x8 af[4], bfr[4];
#pragma unroll
    for (int mb = 0; mb < 4; ++mb)
      af[mb] = *(const bf16x8*)&sA[(wm * 64 + mb * 16 + l15) * 32 + lg * 8];
#pragma unroll
    for (int nb = 0; nb < 4; ++nb)
      bfr[nb] = *(const bf16x8*)&sB[(wn * 64 + nb * 16 + l15) * 32 + lg * 8];
#pragma unroll
    for (int mb = 0; mb < 4; ++mb)
#pragma unroll
      for (int nb = 0; nb < 4; ++nb)
        acc[mb][nb] = __builtin_amdgcn_mfma_f32_16x16x32_bf16(af[mb], bfr[nb], acc[mb][nb], 0, 0, 0);
    __syncthreads();
  }

  const int colb = (int)row0B + wn * 64;
#pragma unroll
  for (int nb = 0; nb < 4; ++nb) {
    int col = colb + nb * 16 + l15;
    float bv = bias[col];
#pragma unroll
    for (int mb = 0; mb < 4; ++mb) {
      size_t rowb = row0A + wm * 64 + mb * 16 + lg * 4;
#pragma unroll
      for (int r = 0; r < 4; ++r)
        C[(rowb + r) * ldc + col] = f2bf(acc[mb][nb][r] + bv);
    }
  }
}

// ---------- flash attention (gamma!=0 path; gamma==0 -> no-op) ----------
#define LDQ 1536
__global__ __launch_bounds__(256) void flash_attn(
    const unsigned short* __restrict__ P,
    const unsigned short* __restrict__ f1,
    const unsigned short* __restrict__ h1b,
    const unsigned short* __restrict__ h2b,
    const float* __restrict__ gamma,
    unsigned short* __restrict__ f1out,
    float* __restrict__ out32,
    int dir)
{
  const float g0 = gamma[0];
  if (g0 == 0.0f) return;  // fused_h12_out already wrote the final output

  __shared__ __align__(16) unsigned short KVs[18432];
  __shared__ __align__(16) float Sred[4608];
  __shared__ __align__(16) unsigned short Pt[1152];
  __shared__ float mstate[32], lstate[32], alpha_s[32];

  const int tid = threadIdx.x;
  const int lane = tid & 63;
  const int w = tid >> 6;
  const int l15 = lane & 15, lg = lane >> 4;
  const int wbase = w * 128;
  const int qt = blockIdx.x;
  const int b = blockIdx.y;
  const size_t qrow0 = (size_t)b * 2048 + (size_t)qt * 32;
  const size_t krow0 = (size_t)b * 2048;

  if (tid < 32) { mstate[tid] = -1e30f; lstate[tid] = 0.f; }
  __syncthreads();

  bf16x8 qf[2][4];
#pragma unroll
  for (int mb = 0; mb < 2; ++mb)
#pragma unroll
    for (int ks = 0; ks < 4; ++ks)
      qf[mb][ks] = *(const bf16x8*)(P + (qrow0 + mb * 16 + l15) * LDQ + wbase + ks * 32 + lg * 8);

  f32x4 o[2][8] = {};

  const int srow = tid >> 3, ssub = tid & 7;
  const int kvp = tid & 15, dg = tid >> 4;

  for (int kt = 0; kt < 64; ++kt) {
    const size_t kvb = krow0 + (size_t)kt * 32;
#pragma unroll
    for (int i = 0; i < 8; ++i) {
      int cc = tid + i * 256;
      int r = cc >> 6, c8 = cc & 63;
      *(u16x8*)&KVs[r * 520 + c8 * 8] = *(const u16x8*)(P + (kvb + r) * LDQ + 512 + c8 * 8);
    }
    __syncthreads();

    f32x4 sacc[2][2] = {};
#pragma unroll
    for (int ks = 0; ks < 4; ++ks)
#pragma unroll
      for (int nb = 0; nb < 2; ++nb) {
        bf16x8 kf = *(const bf16x8*)&KVs[(nb * 16 + l15) * 520 + wbase + ks * 32 + lg * 8];
#pragma unroll
        for (int mb = 0; mb < 2; ++mb)
          sacc[mb][nb] = __builtin_amdgcn_mfma_f32_16x16x32_bf16(qf[mb][ks], kf, sacc[mb][nb], 0, 0, 0);
      }
#pragma unroll
    for (int mb = 0; mb < 2; ++mb)
#pragma unroll
      for (int nb = 0; nb < 2; ++nb)
#pragma unroll
        for (int r = 0; r < 4; ++r)
          Sred[w * 1152 + (mb * 16 + lg * 4 + r) * 36 + nb * 16 + l15] = sacc[mb][nb][r];
    __syncthreads();

    {
      f32x4 sv = {};
#pragma unroll
      for (int w2 = 0; w2 < 4; ++w2)
        sv += *(const f32x4*)&Sred[w2 * 1152 + srow * 36 + ssub * 4];
      const float scale = 0.044194173824159216f;
      sv *= scale;
      float mloc = fmaxf(fmaxf(sv[0], sv[1]), fmaxf(sv[2], sv[3]));
      mloc = fmaxf(mloc, __shfl_xor(mloc, 1));
      mloc = fmaxf(mloc, __shfl_xor(mloc, 2));
      mloc = fmaxf(mloc, __shfl_xor(mloc, 4));
      float mold = mstate[srow];
      float mnew = fmaxf(mold, mloc);
      const float LOG2E = 1.4426950408889634f;
      float p0 = exp2f((sv[0] - mnew) * LOG2E);
      float p1 = exp2f((sv[1] - mnew) * LOG2E);
      float p2 = exp2f((sv[2] - mnew) * LOG2E);
      float p3 = exp2f((sv[3] - mnew) * LOG2E);
      float lloc = p0 + p1 + p2 + p3;
      lloc += __shfl_xor(lloc, 1);
      lloc += __shfl_xor(lloc, 2);
      lloc += __shfl_xor(lloc, 4);
      float alpha = exp2f((mold - mnew) * LOG2E);
      if (ssub == 0) {
        mstate[srow] = mnew;
        lstate[srow] = lstate[srow] * alpha + lloc;
        alpha_s[srow] = alpha;
      }
      u16x4 pw;
      pw[0] = f2bf(p0); pw[1] = f2bf(p1); pw[2] = f2bf(p2); pw[3] = f2bf(p3);
      *(u16x4*)&Pt[srow * 36 + ssub * 4] = pw;
    }
#pragma unroll
    for (int i = 0; i < 4; ++i) {
      int d0 = (dg + i * 16) * 8;
      u16x8 v0 = *(const u16x8*)(P + (kvb + kvp * 2) * LDQ + 1024 + d0);
      u16x8 v1 = *(const u16x8*)(P + (kvb + kvp * 2 + 1) * LDQ + 1024 + d0);
#pragma unroll
      for (int j = 0; j < 8; ++j) {
        u16x2 t2; t2[0] = v0[j]; t2[1] = v1[j];
        *(u16x2*)&KVs[(d0 + j) * 36 + kvp * 2] = t2;
      }
    }
    __syncthreads();

    float al[2][4];
#pragma unroll
    for (int mb = 0; mb < 2; ++mb)
#pragma unroll
      for (int r = 0; r < 4; ++r)
        al[mb][r] = alpha_s[mb * 16 + lg * 4 + r];
#pragma unroll
    for (int mb = 0; mb < 2; ++mb)
#pragma unroll
      for (int nb = 0; nb < 8; ++nb)
#pragma unroll
        for (int r = 0; r < 4; ++r)
          o[mb][nb][r] *= al[mb][r];

    bf16x8 pf[2];
#pragma unroll
    for (int mb = 0; mb < 2; ++mb) {
      u16x4 lo = *(const u16x4*)&Pt[(mb * 16 + l15) * 36 + lg * 8];
      u16x4 hi = *(const u16x4*)&Pt[(mb * 16 + l15) * 36 + lg * 8 + 4];
      pf[mb] = as_bf16x8(__builtin_shufflevector(lo, hi, 0, 1, 2, 3, 4, 5, 6, 7));
    }
#pragma unroll
    for (int nb = 0; nb < 8; ++nb) {
      int d = wbase + nb * 16 + l15;
      u16x4 lo = *(const u16x4*)&KVs[d * 36 + lg * 8];
      u16x4 hi = *(const u16x4*)&KVs[d * 36 + lg * 8 + 4];
      bf16x8 vf = as_bf16x8(__builtin_shufflevector(lo, hi, 0, 1, 2, 3, 4, 5, 6, 7));
#pragma unroll
      for (int mb = 0; mb < 2; ++mb)
        o[mb][nb] = __builtin_amdgcn_mfma_f32_16x16x32_bf16(pf[mb], vf, o[mb][nb], 0, 0, 0);
    }
    __syncthreads();
  }

  float li[2][4];
#pragma unroll
  for (int mb = 0; mb < 2; ++mb)
#pragma unroll
    for (int r = 0; r < 4; ++r)
      li[mb][r] = 1.0f / lstate[mb * 16 + lg * 4 + r];

  if (dir == 0) {
#pragma unroll
    for (int mb = 0; mb < 2; ++mb)
#pragma unroll
      for (int nb = 0; nb < 8; ++nb)
#pragma unroll
        for (int r = 0; r < 4; ++r)
          f1out[(qrow0 + mb * 16 + lg * 4 + r) * 512 + wbase + nb * 16 + l15] =
              f2bf(o[mb][nb][r] * li[mb][r]);
  } else {
    float g = g0;
#pragma unroll
    for (int mb = 0; mb < 2; ++mb)
#pragma unroll
      for (int nb = 0; nb < 8; ++nb)
#pragma unroll
        for (int r = 0; r < 4; ++r) {
          size_t idx = (qrow0 + mb * 16 + lg * 4 + r) * 512 + wbase + nb * 16 + l15;
          float f1v = bf2f(f1[idx]);
          float f2v = o[mb][nb][r] * li[mb][r];
          out32[idx] = g * (f1v + f2v) + bf2f(h1b[idx]) + bf2f(h2b[idx]);
        }
  }
}

// ---------- launch ----------
extern "C" void kernel_launch(void* const* d_in, const int* in_sizes, int n_in,
                              void* d_out, int out_size, void* d_ws, size_t ws_size,
                              hipStream_t stream)
{
  const float* x1    = (const float*)d_in[0];
  const float* x2    = (const float*)d_in[1];
  const float* Wp1   = (const float*)d_in[2];
  const float* bp1   = (const float*)d_in[3];
  const float* Wp2   = (const float*)d_in[4];
  const float* bp2   = (const float*)d_in[5];
  const float* Wq    = (const float*)d_in[6];
  const float* bq    = (const float*)d_in[7];
  const float* Wk    = (const float*)d_in[8];
  const float* bk    = (const float*)d_in[9];
  const float* Wv    = (const float*)d_in[10];
  const float* bv    = (const float*)d_in[11];
  const float* gamma = (const float*)d_in[12];
  float* out = (float*)d_out;
  char* ws = (char*)d_ws;

  unsigned short* WTp1 = (unsigned short*)(ws + 0);          // 512x768 bf16
  unsigned short* WTp2 = (unsigned short*)(ws + 786432);     // 512x1024 bf16
  unsigned short* WTq  = (unsigned short*)(ws + 1835008);    // 512x512 bf16
  unsigned short* WTk  = (unsigned short*)(ws + 2359296);
  unsigned short* WTv  = (unsigned short*)(ws + 2883584);
  unsigned short* h1b  = (unsigned short*)(ws + 3407872);    // 16384x512 bf16
  unsigned short* h2b  = (unsigned short*)(ws + 20185088);   // 16384x512 bf16
  unsigned short* f1b  = (unsigned short*)(ws + 36962304);   // 16384x512 bf16
  unsigned short* P1   = (unsigned short*)(ws + 53739520);   // 16384x1536 bf16
  // gamma==0-only bf16 copies of x1/x2, overlaid on h1b/h2b/f1b space
  // (those buffers are only used by the gamma!=0 path; the x-convert
  // segments are gated off when gamma!=0, so no conflict either way).
  unsigned short* xbf1 = (unsigned short*)(ws + 3407872);    // 16384x768  (25.2 MB)
  unsigned short* xbf2 = (unsigned short*)(ws + 28573696);   // 16384x1024 (33.6 MB)

  // 1: W transposes + gamma==0-gated x1/x2 bf16 conversion (one launch)
  transpose_all_lds<<<14752, 256, 0, stream>>>(Wp1, Wp2, Wq, Wk, Wv, x1, x2,
                                               WTp1, WTp2, WTq, WTk, WTv,
                                               xbf1, xbf2, gamma);

  // 2: gamma==0 fast path — pure async-staged GEMM (64x64 tiles, 5 blk/CU)
  fused_h12_out<<<2048, 256, 0, stream>>>(xbf1, xbf2, WTp1, WTp2, bp1, bp2, out, gamma);

  // 3: gamma!=0 path — h1/h2 bf16 (gated, merged z=2)
  gemm_h12<<<dim3(128, 4, 2), 256, 0, stream>>>(x1, x2, WTp1, WTp2, bp1, bp2, h1b, h2b, gamma);

  // 4-5: direction 0 QKV + attention (gated)
  gemm_qkv<<<dim3(128, 4, 3), 256, 0, stream>>>(h1b, h2b, WTq, WTk, WTv, bq, bk, bv, P1, gamma);
  flash_attn<<<dim3(64, 8), 256, 0, stream>>>(P1, f1b, h1b, h2b, gamma, f1b, out, 0);

  // 6-7: direction 1 QKV + attention/combine (gated)
  gemm_qkv<<<dim3(128, 4, 3), 256, 0, stream>>>(h2b, h1b, WTq, WTk, WTv, bq, bk, bv, P1, gamma);
  flash_attn<<<dim3(64, 8), 256, 0, stream>>>(P1, f1b, h1b, h2b, gamma, f1b, out, 1);
}

// Round 9
// 231.897 us; speedup vs baseline: 1.0691x; 1.0691x over previous
//
#include <hip/hip_runtime.h>
#include <stdint.h>

// Dtype model: inputs fp32, output fp32, internals bf16 MFMA.
// gamma == 0 in this instance => out = h1 + h2 = x1@Wp1 + x2@Wp2 + b1 + b2.
// R14: R13's fused GEMM fetched 231MB vs 60MB compulsory — by=f>>3 put a
// panel's 8 col-sharers on 8 DIFFERENT XCDs (round-robin), 4x L2-fill.
// Remap by=(f&7)|((f>>6)<<3), bx=(f>>3)&7: sharers share f%8 -> same XCD,
// and sit in one 64-block dispatch window -> co-resident. Everything else
// unchanged from R13 (passed, absmax 0.03125).

// ---------- types ----------
typedef __bf16 bf16x8 __attribute__((ext_vector_type(8)));
typedef float f32x4 __attribute__((ext_vector_type(4)));
typedef unsigned short u16x8 __attribute__((ext_vector_type(8)));
typedef unsigned short u16x4 __attribute__((ext_vector_type(4)));
typedef unsigned short u16x2 __attribute__((ext_vector_type(2)));

typedef __attribute__((address_space(3))) unsigned int as3_u32;
typedef const __attribute__((address_space(1))) unsigned int as1_u32;

__device__ __forceinline__ float bf2f(unsigned short h) {
  union { unsigned int u; float f; } v; v.u = ((unsigned int)h) << 16; return v.f;
}
__device__ __forceinline__ unsigned short f2bf(float f) {
  union { float f; unsigned int u; } v; v.f = f;
  unsigned int u = v.u;
  return (unsigned short)((u + 0x7fffu + ((u >> 16) & 1u)) >> 16);
}
__device__ __forceinline__ bf16x8 as_bf16x8(u16x8 x) {
  union { u16x8 u; bf16x8 b; } c; c.u = x; return c.b;
}
// async global->LDS, 16B per lane; lds base must be wave-uniform
__device__ __forceinline__ void async_load16(unsigned short* lds, const unsigned short* g) {
  __builtin_amdgcn_global_load_lds((as1_u32*)g, (as3_u32*)lds, 16, 0, 0);
}

// ---------- transpose + x-convert megakernel ----------
// bids 0..415: dst_bf16[512][K] = W[K][512]^T (LDS-tiled, coalesced both ways);
//   QKV segments (bid>=224) gamma!=0-only.
// bids 416..6559: xbf1 = bf16(x1), 2048 f32/block. gamma==0-only.
// bids 6560..14751: xbf2 = bf16(x2).                gamma==0-only.
__global__ __launch_bounds__(256) void transpose_all_lds(
    const float* __restrict__ Wp1, const float* __restrict__ Wp2,
    const float* __restrict__ Wq, const float* __restrict__ Wk,
    const float* __restrict__ Wv,
    const float* __restrict__ x1, const float* __restrict__ x2,
    unsigned short* __restrict__ o1, unsigned short* __restrict__ o2,
    unsigned short* __restrict__ oq, unsigned short* __restrict__ ok,
    unsigned short* __restrict__ ov,
    unsigned short* __restrict__ xbf1, unsigned short* __restrict__ xbf2,
    const float* __restrict__ gamma)
{
  const int bid = blockIdx.x;
  const int tid = threadIdx.x;

  if (bid >= 416) {
    // streaming fp32 -> bf16 copy of x1/x2 (only the gamma==0 fused path
    // consumes these; buffers overlay h1b/h2b which gamma==0 never uses)
    if (gamma[0] != 0.0f) return;
    const float* src; unsigned short* dst; int local;
    if (bid < 6560) { src = x1; dst = xbf1; local = bid - 416; }
    else            { src = x2; dst = xbf2; local = bid - 6560; }
    size_t base = (size_t)local * 2048 + (size_t)tid * 8;
    f32x4 a = *(const f32x4*)(src + base);
    f32x4 b = *(const f32x4*)(src + base + 4);
    u16x8 o;
#pragma unroll
    for (int j = 0; j < 4; ++j) { o[j] = f2bf(a[j]); o[4 + j] = f2bf(b[j]); }
    *(u16x8*)(dst + base) = o;
    return;
  }

  __shared__ unsigned short sT[64][72];  // [n][k], stride 144B (16B-aligned)
  const float* src; unsigned short* dst; int K, ktiles, base;
  if (bid < 96)       { src = Wp1; dst = o1; K = 768;  ktiles = 12; base = 0; }
  else if (bid < 224) { src = Wp2; dst = o2; K = 1024; ktiles = 16; base = 96; }
  else {
    if (gamma[0] == 0.0f) return;  // QKV weights only feed attention
    K = 512; ktiles = 8;
    if (bid < 288)      { src = Wq; dst = oq; base = 224; }
    else if (bid < 352) { src = Wk; dst = ok; base = 288; }
    else                { src = Wv; dst = ov; base = 352; }
  }
  const int local = bid - base;
  const int k0 = (local % ktiles) * 64;
  const int n0 = (local / ktiles) * 64;

  const int rr = tid >> 4, c4 = tid & 15;
#pragma unroll
  for (int i = 0; i < 4; ++i) {
    int row = i * 16 + rr;
    f32x4 v = *(const f32x4*)(src + (size_t)(k0 + row) * 512 + n0 + c4 * 4);
#pragma unroll
    for (int j = 0; j < 4; ++j)
      sT[c4 * 4 + j][row] = f2bf(v[j]);
  }
  __syncthreads();

  const int nr = tid >> 3, kq = tid & 7;
#pragma unroll
  for (int i = 0; i < 2; ++i) {
    int n = i * 32 + nr;
    *(u16x8*)(dst + (size_t)(n0 + n) * K + k0 + kq * 8) = *(const u16x8*)&sT[n][kq * 8];
  }
}

// ---------- fused gamma==0 output GEMM ----------
// out_f32[16384,512] = xbf1@Wp1 + xbf2@Wp2 + b1 + b2, K = 768+1024 = 1792.
// 64x64 tile, BK=64, dbuf LDS (32 KiB -> 5 blocks/CU). BOTH operands via
// global_load_lds, pre-swizzled global source (linear LDS dest, XOR swizzle
// matched on read). Grid 2048, XCD-grouped remap: by=(f&7)|((f>>6)<<3),
// bx=(f>>3)&7 -> a panel's 8 col-sharers share f%8 (same XCD L2) and sit
// in one 64-block dispatch window (co-resident).
__global__ __launch_bounds__(256, 5) void fused_h12_out(
    const unsigned short* __restrict__ xbf1, const unsigned short* __restrict__ xbf2,
    const unsigned short* __restrict__ WT1, const unsigned short* __restrict__ WT2,
    const float* __restrict__ b1, const float* __restrict__ b2,
    float* __restrict__ out, const float* __restrict__ gamma)
{
  if (gamma[0] != 0.0f) return;  // gamma!=0 handled by the full path
  __shared__ __align__(16) unsigned short sA[2][64 * 64];
  __shared__ __align__(16) unsigned short sB[2][64 * 64];
  const int tid = threadIdx.x;
  const int lane = tid & 63;
  const int w = tid >> 6;
  const int wm = w & 1, wn = w >> 1;
  const int l15 = lane & 15, lg = lane >> 4;

  const int f = blockIdx.x;                       // 0..2047
  const int bx = (f >> 3) & 7;                    // col tile 0..7
  const int by = (f & 7) | ((f >> 6) << 3);       // row panel 0..255
  const size_t row0A = (size_t)by * 64;
  const int row0B = bx * 64;

  f32x4 acc[2][2] = {};

  // tile = 64 rows x 64 bf16 = 512 16B chunks -> 2 gload_lds/thread.
  auto stageA = [&](int kk, int buf) {
#pragma unroll
    for (int j = 0; j < 2; ++j) {
      int cc = (w * 2 + j) * 64 + lane;      // 16B chunk id 0..511
      int r = cc >> 3, c = cc & 7;
      int cs = c ^ (r & 7);                  // pre-swizzled global source
      const unsigned short* ap = (kk < 768)
          ? (xbf1 + (size_t)(row0A + r) * 768 + kk + cs * 8)
          : (xbf2 + (size_t)(row0A + r) * 1024 + (kk - 768) + cs * 8);
      async_load16(&sA[buf][(size_t)(w * 2 + j) * 512], ap);
    }
  };
  auto stageB = [&](int kk, int buf) {
#pragma unroll
    for (int j = 0; j < 2; ++j) {
      int cc = (w * 2 + j) * 64 + lane;
      int r = cc >> 3, c = cc & 7;
      int cs = c ^ (r & 7);
      const unsigned short* bp = (kk < 768)
          ? (WT1 + (size_t)(row0B + r) * 768 + kk + cs * 8)
          : (WT2 + (size_t)(row0B + r) * 1024 + (kk - 768) + cs * 8);
      async_load16(&sB[buf][(size_t)(w * 2 + j) * 512], bp);
    }
  };
  auto compute = [&](int buf) {
#pragma unroll
    for (int ks = 0; ks < 2; ++ks) {
      bf16x8 af[2], bfr[2];
#pragma unroll
      for (int mb = 0; mb < 2; ++mb) {
        int row = wm * 32 + mb * 16 + l15;
        int cs = (ks * 4 + lg) ^ (row & 7);
        af[mb] = *(const bf16x8*)&sA[buf][row * 64 + cs * 8];
      }
#pragma unroll
      for (int nb = 0; nb < 2; ++nb) {
        int row = wn * 32 + nb * 16 + l15;
        int cs = (ks * 4 + lg) ^ (row & 7);
        bfr[nb] = *(const bf16x8*)&sB[buf][row * 64 + cs * 8];
      }
#pragma unroll
      for (int mb = 0; mb < 2; ++mb)
#pragma unroll
        for (int nb = 0; nb < 2; ++nb)
          acc[mb][nb] = __builtin_amdgcn_mfma_f32_16x16x32_bf16(af[mb], bfr[nb], acc[mb][nb], 0, 0, 0);
    }
  };

  // prologue: stage tile 0
  stageA(0, 0);
  stageB(0, 0);
  __syncthreads();

  const int NT = 28;  // 1792 / 64
  int cur = 0;
  for (int t = 0; t < NT; ++t) {
    if (t + 1 < NT) {            // issue next tile's loads BEFORE compute
      stageA((t + 1) * 64, cur ^ 1);
      stageB((t + 1) * 64, cur ^ 1);
    }
    compute(cur);
    __syncthreads();             // drains next-tile gload_lds
    cur ^= 1;
  }

  // epilogue: fp32 direct store, bias = b1 + b2
  const int colb = row0B + wn * 32;
#pragma unroll
  for (int nb = 0; nb < 2; ++nb) {
    int col = colb + nb * 16 + l15;
    float bv = b1[col] + b2[col];
#pragma unroll
    for (int mb = 0; mb < 2; ++mb) {
      size_t rowb = row0A + wm * 32 + mb * 16 + lg * 4;
#pragma unroll
      for (int r = 0; r < 4; ++r)
        out[(rowb + r) * 512 + col] = acc[mb][nb][r] + bv;
    }
  }
}

// ---------- gated h-GEMMs (gamma!=0 path): z=0 -> h1, z=1 -> h2 ----------
__global__ __launch_bounds__(256) void gemm_h12(
    const float* __restrict__ x1, const float* __restrict__ x2,
    const unsigned short* __restrict__ WT1, const unsigned short* __restrict__ WT2,
    const float* __restrict__ b1, const float* __restrict__ b2,
    unsigned short* __restrict__ h1b, unsigned short* __restrict__ h2b,
    const float* __restrict__ gate)
{
  if (gate[0] == 0.0f) return;
  const int z = blockIdx.z;
  const float* A = z ? x2 : x1;
  const unsigned short* Bt = z ? WT2 : WT1;
  const float* bias = z ? b2 : b1;
  unsigned short* C = z ? h2b : h1b;
  const int K = z ? 1024 : 768;
  const int ldc = 512;

  __shared__ __align__(16) unsigned short sA[128 * 32];
  __shared__ __align__(16) unsigned short sB[128 * 32];
  const int tid = threadIdx.x;
  const int lane = tid & 63;
  const int w = tid >> 6;
  const int wm = w & 1, wn = w >> 1;
  const int l15 = lane & 15, lg = lane >> 4;
  const size_t row0A = (size_t)blockIdx.x * 128;
  const size_t row0B = (size_t)blockIdx.y * 128;
  f32x4 acc[4][4] = {};

  for (int kb = 0; kb < K; kb += 32) {
#pragma unroll
    for (int j = 0; j < 2; ++j) {
      int cc = (w * 2 + j) * 64 + lane;
      int r = cc >> 2, k8 = cc & 3;
      async_load16(&sB[(size_t)((w * 2 + j) * 64) * 8], Bt + (row0B + r) * K + kb + k8 * 8);
    }
    {
      // coalesced A staging: 128x32 f32 tile = 1024 f32x4 chunks, 4/thread
#pragma unroll
      for (int i = 0; i < 4; ++i) {
        int cc = i * 256 + tid;
        int row = cc >> 3, c4 = cc & 7;     // 8 chunks per 32-float row
        f32x4 v = *(const f32x4*)(A + (row0A + row) * K + kb + c4 * 4);
        u16x4 hv;
#pragma unroll
        for (int j = 0; j < 4; ++j) hv[j] = f2bf(v[j]);
        *(u16x4*)&sA[row * 32 + c4 * 4] = hv;
      }
    }
    __syncthreads();
    bf16x8 af[4], bfr[4];
#pragma unroll
    for (int mb = 0; mb < 4; ++mb)
      af[mb] = *(const bf16x8*)&sA[(wm * 64 + mb * 16 + l15) * 32 + lg * 8];
#pragma unroll
    for (int nb = 0; nb < 4; ++nb)
      bfr[nb] = *(const bf16x8*)&sB[(wn * 64 + nb * 16 + l15) * 32 + lg * 8];
#pragma unroll
    for (int mb = 0; mb < 4; ++mb)
#pragma unroll
      for (int nb = 0; nb < 4; ++nb)
        acc[mb][nb] = __builtin_amdgcn_mfma_f32_16x16x32_bf16(af[mb], bfr[nb], acc[mb][nb], 0, 0, 0);
    __syncthreads();
  }

  const int colb = (int)row0B + wn * 64;
#pragma unroll
  for (int nb = 0; nb < 4; ++nb) {
    int col = colb + nb * 16 + l15;
    float bv = bias[col];
#pragma unroll
    for (int mb = 0; mb < 4; ++mb) {
      size_t rowb = row0A + wm * 64 + mb * 16 + lg * 4;
#pragma unroll
      for (int r = 0; r < 4; ++r)
        C[(rowb + r) * ldc + col] = f2bf(acc[mb][nb][r] + bv);
    }
  }
}

// ---------- QKV projections: 3 GEMMs in one launch via blockIdx.z ----------
__global__ __launch_bounds__(256) void gemm_qkv(
    const unsigned short* __restrict__ Aq,
    const unsigned short* __restrict__ Akv,
    const unsigned short* __restrict__ Wq_, const unsigned short* __restrict__ Wk_,
    const unsigned short* __restrict__ Wv_,
    const float* __restrict__ bq_, const float* __restrict__ bk_,
    const float* __restrict__ bv_,
    unsigned short* __restrict__ P,
    const float* __restrict__ gate)
{
  if (gate[0] == 0.0f) return;
  const int z = blockIdx.z;
  const unsigned short* A  = (z == 0) ? Aq : Akv;
  const unsigned short* Bt = (z == 0) ? Wq_ : (z == 1 ? Wk_ : Wv_);
  const float* bias        = (z == 0) ? bq_ : (z == 1 ? bk_ : bv_);
  unsigned short* C = P + z * 512;
  const int K = 512, ldc = 1536;

  __shared__ __align__(16) unsigned short sA[128 * 32];
  __shared__ __align__(16) unsigned short sB[128 * 32];
  const int tid = threadIdx.x;
  const int lane = tid & 63;
  const int w = tid >> 6;
  const int wm = w & 1, wn = w >> 1;
  const int l15 = lane & 15, lg = lane >> 4;
  const size_t row0A = (size_t)blockIdx.x * 128;
  const size_t row0B = (size_t)blockIdx.y * 128;
  f32x4 acc[4][4] = {};

  for (int kb = 0; kb < K; kb += 32) {
#pragma unroll
    for (int j = 0; j < 2; ++j) {
      int cc = (w * 2 + j) * 64 + lane;
      int r = cc >> 2, k8 = cc & 3;
      async_load16(&sA[(size_t)((w * 2 + j) * 64) * 8], A + (row0A + r) * K + kb + k8 * 8);
      async_load16(&sB[(size_t)((w * 2 + j) * 64) * 8], Bt + (row0B + r) * K + kb + k8 * 8);
    }
    __syncthreads();
    bf16x8 af[4], bfr[4];
#pragma unroll
    for (int mb = 0; mb < 4; ++mb)
      af[mb] = *(const bf16x8*)&sA[(wm * 64 + mb * 16 + l15) * 32 + lg * 8];
#pragma unroll
    for (int nb = 0; nb < 4; ++nb)
      bfr[nb] = *(const bf16x8*)&sB[(wn * 64 + nb * 16 + l15) * 32 + lg * 8];
#pragma unroll
    for (int mb = 0; mb < 4; ++mb)
#pragma unroll
      for (int nb = 0; nb < 4; ++nb)
        acc[mb][nb] = __builtin_amdgcn_mfma_f32_16x16x32_bf16(af[mb], bfr[nb], acc[mb][nb], 0, 0, 0);
    __syncthreads();
  }

  const int colb = (int)row0B + wn * 64;
#pragma unroll
  for (int nb = 0; nb < 4; ++nb) {
    int col = colb + nb * 16 + l15;
    float bv = bias[col];
#pragma unroll
    for (int mb = 0; mb < 4; ++mb) {
      size_t rowb = row0A + wm * 64 + mb * 16 + lg * 4;
#pragma unroll
      for (int r = 0; r < 4; ++r)
        C[(rowb + r) * ldc + col] = f2bf(acc[mb][nb][r] + bv);
    }
  }
}

// ---------- flash attention (gamma!=0 path; gamma==0 -> no-op) ----------
#define LDQ 1536
__global__ __launch_bounds__(256) void flash_attn(
    const unsigned short* __restrict__ P,
    const unsigned short* __restrict__ f1,
    const unsigned short* __restrict__ h1b,
    const unsigned short* __restrict__ h2b,
    const float* __restrict__ gamma,
    unsigned short* __restrict__ f1out,
    float* __restrict__ out32,
    int dir)
{
  const float g0 = gamma[0];
  if (g0 == 0.0f) return;  // fused_h12_out already wrote the final output

  __shared__ __align__(16) unsigned short KVs[18432];
  __shared__ __align__(16) float Sred[4608];
  __shared__ __align__(16) unsigned short Pt[1152];
  __shared__ float mstate[32], lstate[32], alpha_s[32];

  const int tid = threadIdx.x;
  const int lane = tid & 63;
  const int w = tid >> 6;
  const int l15 = lane & 15, lg = lane >> 4;
  const int wbase = w * 128;
  const int qt = blockIdx.x;
  const int b = blockIdx.y;
  const size_t qrow0 = (size_t)b * 2048 + (size_t)qt * 32;
  const size_t krow0 = (size_t)b * 2048;

  if (tid < 32) { mstate[tid] = -1e30f; lstate[tid] = 0.f; }
  __syncthreads();

  bf16x8 qf[2][4];
#pragma unroll
  for (int mb = 0; mb < 2; ++mb)
#pragma unroll
    for (int ks = 0; ks < 4; ++ks)
      qf[mb][ks] = *(const bf16x8*)(P + (qrow0 + mb * 16 + l15) * LDQ + wbase + ks * 32 + lg * 8);

  f32x4 o[2][8] = {};

  const int srow = tid >> 3, ssub = tid & 7;
  const int kvp = tid & 15, dg = tid >> 4;

  for (int kt = 0; kt < 64; ++kt) {
    const size_t kvb = krow0 + (size_t)kt * 32;
#pragma unroll
    for (int i = 0; i < 8; ++i) {
      int cc = tid + i * 256;
      int r = cc >> 6, c8 = cc & 63;
      *(u16x8*)&KVs[r * 520 + c8 * 8] = *(const u16x8*)(P + (kvb + r) * LDQ + 512 + c8 * 8);
    }
    __syncthreads();

    f32x4 sacc[2][2] = {};
#pragma unroll
    for (int ks = 0; ks < 4; ++ks)
#pragma unroll
      for (int nb = 0; nb < 2; ++nb) {
        bf16x8 kf = *(const bf16x8*)&KVs[(nb * 16 + l15) * 520 + wbase + ks * 32 + lg * 8];
#pragma unroll
        for (int mb = 0; mb < 2; ++mb)
          sacc[mb][nb] = __builtin_amdgcn_mfma_f32_16x16x32_bf16(qf[mb][ks], kf, sacc[mb][nb], 0, 0, 0);
      }
#pragma unroll
    for (int mb = 0; mb < 2; ++mb)
#pragma unroll
      for (int nb = 0; nb < 2; ++nb)
#pragma unroll
        for (int r = 0; r < 4; ++r)
          Sred[w * 1152 + (mb * 16 + lg * 4 + r) * 36 + nb * 16 + l15] = sacc[mb][nb][r];
    __syncthreads();

    {
      f32x4 sv = {};
#pragma unroll
      for (int w2 = 0; w2 < 4; ++w2)
        sv += *(const f32x4*)&Sred[w2 * 1152 + srow * 36 + ssub * 4];
      const float scale = 0.044194173824159216f;
      sv *= scale;
      float mloc = fmaxf(fmaxf(sv[0], sv[1]), fmaxf(sv[2], sv[3]));
      mloc = fmaxf(mloc, __shfl_xor(mloc, 1));
      mloc = fmaxf(mloc, __shfl_xor(mloc, 2));
      mloc = fmaxf(mloc, __shfl_xor(mloc, 4));
      float mold = mstate[srow];
      float mnew = fmaxf(mold, mloc);
      const float LOG2E = 1.4426950408889634f;
      float p0 = exp2f((sv[0] - mnew) * LOG2E);
      float p1 = exp2f((sv[1] - mnew) * LOG2E);
      float p2 = exp2f((sv[2] - mnew) * LOG2E);
      float p3 = exp2f((sv[3] - mnew) * LOG2E);
      float lloc = p0 + p1 + p2 + p3;
      lloc += __shfl_xor(lloc, 1);
      lloc += __shfl_xor(lloc, 2);
      lloc += __shfl_xor(lloc, 4);
      float alpha = exp2f((mold - mnew) * LOG2E);
      if (ssub == 0) {
        mstate[srow] = mnew;
        lstate[srow] = lstate[srow] * alpha + lloc;
        alpha_s[srow] = alpha;
      }
      u16x4 pw;
      pw[0] = f2bf(p0); pw[1] = f2bf(p1); pw[2] = f2bf(p2); pw[3] = f2bf(p3);
      *(u16x4*)&Pt[srow * 36 + ssub * 4] = pw;
    }
#pragma unroll
    for (int i = 0; i < 4; ++i) {
      int d0 = (dg + i * 16) * 8;
      u16x8 v0 = *(const u16x8*)(P + (kvb + kvp * 2) * LDQ + 1024 + d0);
      u16x8 v1 = *(const u16x8*)(P + (kvb + kvp * 2 + 1) * LDQ + 1024 + d0);
#pragma unroll
      for (int j = 0; j < 8; ++j) {
        u16x2 t2; t2[0] = v0[j]; t2[1] = v1[j];
        *(u16x2*)&KVs[(d0 + j) * 36 + kvp * 2] = t2;
      }
    }
    __syncthreads();

    float al[2][4];
#pragma unroll
    for (int mb = 0; mb < 2; ++mb)
#pragma unroll
      for (int r = 0; r < 4; ++r)
        al[mb][r] = alpha_s[mb * 16 + lg * 4 + r];
#pragma unroll
    for (int mb = 0; mb < 2; ++mb)
#pragma unroll
      for (int nb = 0; nb < 8; ++nb)
#pragma unroll
        for (int r = 0; r < 4; ++r)
          o[mb][nb][r] *= al[mb][r];

    bf16x8 pf[2];
#pragma unroll
    for (int mb = 0; mb < 2; ++mb) {
      u16x4 lo = *(const u16x4*)&Pt[(mb * 16 + l15) * 36 + lg * 8];
      u16x4 hi = *(const u16x4*)&Pt[(mb * 16 + l15) * 36 + lg * 8 + 4];
      pf[mb] = as_bf16x8(__builtin_shufflevector(lo, hi, 0, 1, 2, 3, 4, 5, 6, 7));
    }
#pragma unroll
    for (int nb = 0; nb < 8; ++nb) {
      int d = wbase + nb * 16 + l15;
      u16x4 lo = *(const u16x4*)&KVs[d * 36 + lg * 8];
      u16x4 hi = *(const u16x4*)&KVs[d * 36 + lg * 8 + 4];
      bf16x8 vf = as_bf16x8(__builtin_shufflevector(lo, hi, 0, 1, 2, 3, 4, 5, 6, 7));
#pragma unroll
      for (int mb = 0; mb < 2; ++mb)
        o[mb][nb] = __builtin_amdgcn_mfma_f32_16x16x32_bf16(pf[mb], vf, o[mb][nb], 0, 0, 0);
    }
    __syncthreads();
  }

  float li[2][4];
#pragma unroll
  for (int mb = 0; mb < 2; ++mb)
#pragma unroll
    for (int r = 0; r < 4; ++r)
      li[mb][r] = 1.0f / lstate[mb * 16 + lg * 4 + r];

  if (dir == 0) {
#pragma unroll
    for (int mb = 0; mb < 2; ++mb)
#pragma unroll
      for (int nb = 0; nb < 8; ++nb)
#pragma unroll
        for (int r = 0; r < 4; ++r)
          f1out[(qrow0 + mb * 16 + lg * 4 + r) * 512 + wbase + nb * 16 + l15] =
              f2bf(o[mb][nb][r] * li[mb][r]);
  } else {
    float g = g0;
#pragma unroll
    for (int mb = 0; mb < 2; ++mb)
#pragma unroll
      for (int nb = 0; nb < 8; ++nb)
#pragma unroll
        for (int r = 0; r < 4; ++r) {
          size_t idx = (qrow0 + mb * 16 + lg * 4 + r) * 512 + wbase + nb * 16 + l15;
          float f1v = bf2f(f1[idx]);
          float f2v = o[mb][nb][r] * li[mb][r];
          out32[idx] = g * (f1v + f2v) + bf2f(h1b[idx]) + bf2f(h2b[idx]);
        }
  }
}

// ---------- launch ----------
extern "C" void kernel_launch(void* const* d_in, const int* in_sizes, int n_in,
                              void* d_out, int out_size, void* d_ws, size_t ws_size,
                              hipStream_t stream)
{
  const float* x1    = (const float*)d_in[0];
  const float* x2    = (const float*)d_in[1];
  const float* Wp1   = (const float*)d_in[2];
  const float* bp1   = (const float*)d_in[3];
  const float* Wp2   = (const float*)d_in[4];
  const float* bp2   = (const float*)d_in[5];
  const float* Wq    = (const float*)d_in[6];
  const float* bq    = (const float*)d_in[7];
  const float* Wk    = (const float*)d_in[8];
  const float* bk    = (const float*)d_in[9];
  const float* Wv    = (const float*)d_in[10];
  const float* bv    = (const float*)d_in[11];
  const float* gamma = (const float*)d_in[12];
  float* out = (float*)d_out;
  char* ws = (char*)d_ws;

  unsigned short* WTp1 = (unsigned short*)(ws + 0);          // 512x768 bf16
  unsigned short* WTp2 = (unsigned short*)(ws + 786432);     // 512x1024 bf16
  unsigned short* WTq  = (unsigned short*)(ws + 1835008);    // 512x512 bf16
  unsigned short* WTk  = (unsigned short*)(ws + 2359296);
  unsigned short* WTv  = (unsigned short*)(ws + 2883584);
  unsigned short* h1b  = (unsigned short*)(ws + 3407872);    // 16384x512 bf16
  unsigned short* h2b  = (unsigned short*)(ws + 20185088);   // 16384x512 bf16
  unsigned short* f1b  = (unsigned short*)(ws + 36962304);   // 16384x512 bf16
  unsigned short* P1   = (unsigned short*)(ws + 53739520);   // 16384x1536 bf16
  // gamma==0-only bf16 copies of x1/x2, overlaid on h1b/h2b/f1b space
  // (those buffers are only used by the gamma!=0 path; the x-convert
  // segments are gated off when gamma!=0, so no conflict either way).
  unsigned short* xbf1 = (unsigned short*)(ws + 3407872);    // 16384x768  (25.2 MB)
  unsigned short* xbf2 = (unsigned short*)(ws + 28573696);   // 16384x1024 (33.6 MB)

  // 1: W transposes + gamma==0-gated x1/x2 bf16 conversion (one launch)
  transpose_all_lds<<<14752, 256, 0, stream>>>(Wp1, Wp2, Wq, Wk, Wv, x1, x2,
                                               WTp1, WTp2, WTq, WTk, WTv,
                                               xbf1, xbf2, gamma);

  // 2: gamma==0 fast path — pure async-staged GEMM (64x64 tiles, 5 blk/CU)
  fused_h12_out<<<2048, 256, 0, stream>>>(xbf1, xbf2, WTp1, WTp2, bp1, bp2, out, gamma);

  // 3: gamma!=0 path — h1/h2 bf16 (gated, merged z=2)
  gemm_h12<<<dim3(128, 4, 2), 256, 0, stream>>>(x1, x2, WTp1, WTp2, bp1, bp2, h1b, h2b, gamma);

  // 4-5: direction 0 QKV + attention (gated)
  gemm_qkv<<<dim3(128, 4, 3), 256, 0, stream>>>(h1b, h2b, WTq, WTk, WTv, bq, bk, bv, P1, gamma);
  flash_attn<<<dim3(64, 8), 256, 0, stream>>>(P1, f1b, h1b, h2b, gamma, f1b, out, 0);

  // 6-7: direction 1 QKV + attention/combine (gated)
  gemm_qkv<<<dim3(128, 4, 3), 256, 0, stream>>>(h2b, h1b, WTq, WTk, WTv, bq, bk, bv, P1, gamma);
  flash_attn<<<dim3(64, 8), 256, 0, stream>>>(P1, f1b, h1b, h2b, gamma, f1b, out, 1);
}